// Round 3
// 1928.807 us; speedup vs baseline: 1.0422x; 1.0422x over previous
//
#include <hip/hip_runtime.h>
#include <hip/hip_bf16.h>
#include <math.h>

// Problem constants. Inputs/outputs are fp32 (reference dtype); MFMA compute
// uses bf16 hi+lo compensated splitting for fp32-accurate logits.
#define BB    4
#define NV    4096
#define NT    1024
#define VDIM  1024
#define TDIM  1024
#define HEADS 8
#define DHEAD 128   // TDIM / HEADS

typedef __bf16 bf16x8 __attribute__((ext_vector_type(8)));
typedef float  f32x4  __attribute__((ext_vector_type(4)));

__device__ __forceinline__ bf16x8 load8(const __bf16* p) {
    return *reinterpret_cast<const bf16x8*>(p);
}
__device__ __forceinline__ void store8(__bf16* p, bf16x8 v) {
    *reinterpret_cast<bf16x8*>(p) = v;
}
// Load 8 fp32, split each into bf16 hi + bf16 lo (x = hi + lo + O(2^-18 x)).
__device__ __forceinline__ void split8(const float* __restrict__ p,
                                       bf16x8& hi, bf16x8& lo) {
    const f32x4 v0 = *reinterpret_cast<const f32x4*>(p);
    const f32x4 v1 = *reinterpret_cast<const f32x4*>(p + 4);
#pragma unroll
    for (int j = 0; j < 4; j++) {
        const __bf16 h0 = (__bf16)v0[j];
        hi[j] = h0; lo[j] = (__bf16)(v0[j] - (float)h0);
        const __bf16 h1 = (__bf16)v1[j];
        hi[4 + j] = h1; lo[4 + j] = (__bf16)(v1[j] - (float)h1);
    }
}

// ---------------------------------------------------------------------------
// Kernel 1: vc = visual @ W^T  (fp32 in, fp32-accurate via 3-MFMA hi/lo).
// vc stored as bf16 hi+lo pair so QK^T can rebuild fp32-exact logits.
// 128x128 block tile, 4 waves of 64x64. MFMA 16x16x32 bf16.  (unchanged)
// ---------------------------------------------------------------------------
__global__ __launch_bounds__(256) void gemm1_kernel(
    const float* __restrict__ visual,   // [B*NV, VDIM]
    const float* __restrict__ W,        // [TDIM, VDIM]
    __bf16* __restrict__ vc_hi,         // [B*NV, TDIM]
    __bf16* __restrict__ vc_lo)
{
    const int lane = threadIdx.x & 63;
    const int wave = threadIdx.x >> 6;
    const int wm = wave >> 1, wn = wave & 1;
    const int m0 = blockIdx.y * 128 + wm * 64;
    const int n0 = blockIdx.x * 128 + wn * 64;
    const int lrow = lane & 15;
    const int lk8  = (lane >> 4) * 8;

    f32x4 acc[4][4];
#pragma unroll
    for (int i = 0; i < 4; i++)
#pragma unroll
        for (int j = 0; j < 4; j++) acc[i][j] = (f32x4){0.f, 0.f, 0.f, 0.f};

    for (int k0 = 0; k0 < VDIM; k0 += 32) {
        bf16x8 bh[4], bl[4];
#pragma unroll
        for (int nt = 0; nt < 4; nt++)
            split8(W + (size_t)(n0 + nt * 16 + lrow) * VDIM + k0 + lk8, bh[nt], bl[nt]);
#pragma unroll
        for (int mt = 0; mt < 4; mt++) {
            bf16x8 ah, al;
            split8(visual + (size_t)(m0 + mt * 16 + lrow) * VDIM + k0 + lk8, ah, al);
#pragma unroll
            for (int nt = 0; nt < 4; nt++) {
                acc[mt][nt] = __builtin_amdgcn_mfma_f32_16x16x32_bf16(ah, bh[nt], acc[mt][nt], 0, 0, 0);
                acc[mt][nt] = __builtin_amdgcn_mfma_f32_16x16x32_bf16(ah, bl[nt], acc[mt][nt], 0, 0, 0);
                acc[mt][nt] = __builtin_amdgcn_mfma_f32_16x16x32_bf16(al, bh[nt], acc[mt][nt], 0, 0, 0);
            }
        }
    }

    const int r0 = (lane >> 4) * 4;
#pragma unroll
    for (int mt = 0; mt < 4; mt++)
#pragma unroll
        for (int nt = 0; nt < 4; nt++)
#pragma unroll
            for (int r = 0; r < 4; r++) {
                const int row = m0 + mt * 16 + r0 + r;
                const int col = n0 + nt * 16 + lrow;
                const float v = acc[mt][nt][r];
                const __bf16 h = (__bf16)v;          // RNE
                const __bf16 lo = (__bf16)(v - (float)h);
                const size_t idx = (size_t)row * TDIM + col;
                vc_hi[idx] = h;
                vc_lo[idx] = lo;
            }
}

// ---------------------------------------------------------------------------
// Kernel 2: kT[bh][d][kv] = vc_hi[b][kv][h*128+d]  (per-head transposed K so
// PV's B-operand fragments are contiguous-in-kv). 64x64 LDS tile, +8 pad.
// (unchanged)
// ---------------------------------------------------------------------------
__global__ __launch_bounds__(256) void transpose_kernel(
    const __bf16* __restrict__ vc_hi,   // [B, NV, TDIM]
    __bf16* __restrict__ kT)            // [B*H, DHEAD, NV]
{
    __shared__ __bf16 tile[64][72];
    const int bh = blockIdx.z;
    const int b = bh >> 3, h = bh & 7;
    const int kv0 = blockIdx.x * 64;
    const int d0  = blockIdx.y * 64;
    const int t = threadIdx.x;

#pragma unroll
    for (int it = 0; it < 2; it++) {
        const int kvl = (t >> 3) + it * 32;
        const int dl  = (t & 7) * 8;
        bf16x8 v = load8(vc_hi + (size_t)(b * NV + kv0 + kvl) * TDIM + h * DHEAD + d0 + dl);
#pragma unroll
        for (int j = 0; j < 8; j++) tile[kvl][dl + j] = v[j];
    }
    __syncthreads();
#pragma unroll
    for (int it = 0; it < 2; it++) {
        const int dl  = (t >> 3) + it * 32;
        const int kvl = (t & 7) * 8;
        bf16x8 v;
#pragma unroll
        for (int j = 0; j < 8; j++) v[j] = tile[kvl + j][dl];
        store8(kT + (size_t)(bh * DHEAD + d0 + dl) * NV + kv0 + kvl, v);
    }
}

// ---------------------------------------------------------------------------
// Kernel 3: fused attention, 8 waves (512 thr). Occupancy fix vs the 4-wave
// version: grid is only 512 blocks (2 blocks/CU), which capped the old
// kernel at 8 waves/CU = 24% occupancy (latency-bound, MfmaUtil 7%).
// Wave = half*4 + wq: `half` owns one 2048-kv chunk, `wq` owns q-rows
// [q0+wq*16, +16). 2 blocks/CU x 8 waves = 16 waves/CU (the VGPR<=128 cap).
//   pass 1: per-half running (m,l); combine across halves via 1 KB LDS.
//   pass 2: per-half recompute S, write normalized attn fp32 directly,
//           accumulate partial O; halves sum O through a separate 32 KB LDS
//           buffer (NO aliasing — total 52.2 KB/block, 2 blocks/CU = 104 KB
//           of 160 KB, so the separate buffer costs no occupancy).
// No global partial buffers -> workspace identical to the proven 100.7 MB.
// ---------------------------------------------------------------------------
__global__ __launch_bounds__(512, 4) void attn_kernel(
    const float* __restrict__ textual,  // [B, NT, TDIM] fp32
    const __bf16* __restrict__ vc_hi,   // [B, NV, TDIM]
    const __bf16* __restrict__ vc_lo,
    const __bf16* __restrict__ kT,      // [B*H, DHEAD, NV]
    float* __restrict__ out,            // [B, NT, TDIM] fp32
    float* __restrict__ attn)           // [B*H, NT, NV] fp32
{
    __shared__ __bf16 lds_p[8][16][72]; // 8 wave-private P stripes (18.4 KB)
    __shared__ float  obuf[64][128];    // O-exchange between halves (32 KB)
    __shared__ float2 ml_sh[2][64];     // per-half (m,l) per q-row (1 KB)

    const int bh = blockIdx.y;
    const int b = bh >> 3, h = bh & 7;
    const int q0 = blockIdx.x * 64;
    const int lane = threadIdx.x & 63;
    const int wave = threadIdx.x >> 6;  // 0..7
    const int half = wave >> 2;         // kv chunk: 0 -> [0,2048), 1 -> [2048,4096)
    const int wq   = wave & 3;          // q sub-tile within the 64-row block
    const int lrow = lane & 15;
    const int quad = lane >> 4;
    const int lk8  = quad * 8;
    const int qw = q0 + wq * 16;        // this wave's q base

    // Q fragments (hi/lo): A[m=lane&15][k], d=128 -> 4 k-steps of 32
    bf16x8 qh[4], ql[4];
#pragma unroll
    for (int ks = 0; ks < 4; ks++)
        split8(textual + (size_t)(b * NT + qw + lrow) * TDIM + h * DHEAD + ks * 32 + lk8,
               qh[ks], ql[ks]);

    const __bf16* khi_base = vc_hi + (size_t)b * NV * TDIM + h * DHEAD;
    const __bf16* klo_base = vc_lo + (size_t)b * NV * TDIM + h * DHEAD;

    const int kt0 = half * (NV / 128);  // 32 tiles of 64 kv per half
    const int kt1 = kt0 + (NV / 128);

    float m_run[4], l_run[4];
#pragma unroll
    for (int r = 0; r < 4; r++) { m_run[r] = -INFINITY; l_run[r] = 0.f; }

    // ---- pass 1: running max & denom over this wave's kv half ----
    for (int kt = kt0; kt < kt1; kt++) {
        const int kv0 = kt * 64;
        f32x4 acc[4];
#pragma unroll
        for (int c = 0; c < 4; c++) acc[c] = (f32x4){0.f, 0.f, 0.f, 0.f};
#pragma unroll
        for (int c = 0; c < 4; c++) {
            const size_t rowb = (size_t)(kv0 + c * 16 + lrow) * TDIM;
#pragma unroll
            for (int ks = 0; ks < 4; ks++) {
                bf16x8 kh = load8(khi_base + rowb + ks * 32 + lk8);
                bf16x8 kl = load8(klo_base + rowb + ks * 32 + lk8);
                acc[c] = __builtin_amdgcn_mfma_f32_16x16x32_bf16(qh[ks], kh, acc[c], 0, 0, 0);
                acc[c] = __builtin_amdgcn_mfma_f32_16x16x32_bf16(qh[ks], kl, acc[c], 0, 0, 0);
                acc[c] = __builtin_amdgcn_mfma_f32_16x16x32_bf16(ql[ks], kh, acc[c], 0, 0, 0);
            }
        }
#pragma unroll
        for (int r = 0; r < 4; r++) {
            float tm = fmaxf(fmaxf(acc[0][r], acc[1][r]), fmaxf(acc[2][r], acc[3][r]));
#pragma unroll
            for (int off = 1; off < 16; off <<= 1)
                tm = fmaxf(tm, __shfl_xor(tm, off, 64));
            const float nm = fmaxf(m_run[r], tm);
            float ps = __expf(acc[0][r] - nm) + __expf(acc[1][r] - nm) +
                       __expf(acc[2][r] - nm) + __expf(acc[3][r] - nm);
#pragma unroll
            for (int off = 1; off < 16; off <<= 1)
                ps += __shfl_xor(ps, off, 64);
            l_run[r] = l_run[r] * __expf(m_run[r] - nm) + ps;
            m_run[r] = nm;
        }
    }

    // ---- combine per-half (m,l) across the two halves via LDS ----
    // After the 16-wide butterfly all 16 lanes of a quad hold identical
    // (m,l); lane lrow==0 of each quad publishes its 4 rows.
    if (lrow == 0) {
#pragma unroll
        for (int r = 0; r < 4; r++)
            ml_sh[half][wq * 16 + quad * 4 + r] = make_float2(m_run[r], l_run[r]);
    }
    __syncthreads();

    float m_fin[4], inv_l[4];
#pragma unroll
    for (int r = 0; r < 4; r++) {
        const int row = wq * 16 + quad * 4 + r;
        const float2 p0 = ml_sh[0][row];
        const float2 p1 = ml_sh[1][row];
        const float m = fmaxf(p0.x, p1.x);
        const float l = p0.y * __expf(p0.x - m) + p1.y * __expf(p1.x - m);
        m_fin[r] = m;
        inv_l[r] = 1.0f / l;
    }

    f32x4 oacc[8];
#pragma unroll
    for (int c = 0; c < 8; c++) oacc[c] = (f32x4){0.f, 0.f, 0.f, 0.f};

    float* attn_base = attn + (size_t)bh * NT * NV;
    const __bf16* kT_base = kT + (size_t)bh * DHEAD * NV;

    // ---- pass 2: recompute S, emit normalized attn, accumulate partial O ----
    for (int kt = kt0; kt < kt1; kt++) {
        const int kv0 = kt * 64;
        f32x4 acc[4];
#pragma unroll
        for (int c = 0; c < 4; c++) acc[c] = (f32x4){0.f, 0.f, 0.f, 0.f};
#pragma unroll
        for (int c = 0; c < 4; c++) {
            const size_t rowb = (size_t)(kv0 + c * 16 + lrow) * TDIM;
#pragma unroll
            for (int ks = 0; ks < 4; ks++) {
                bf16x8 kh = load8(khi_base + rowb + ks * 32 + lk8);
                bf16x8 kl = load8(klo_base + rowb + ks * 32 + lk8);
                acc[c] = __builtin_amdgcn_mfma_f32_16x16x32_bf16(qh[ks], kh, acc[c], 0, 0, 0);
                acc[c] = __builtin_amdgcn_mfma_f32_16x16x32_bf16(qh[ks], kl, acc[c], 0, 0, 0);
                acc[c] = __builtin_amdgcn_mfma_f32_16x16x32_bf16(ql[ks], kh, acc[c], 0, 0, 0);
            }
        }
        // p: fp32 -> attn directly (coalesced 64B per 16-lane group);
        // bf16 -> wave-private LDS stripe for the PV A-operand transpose.
#pragma unroll
        for (int c = 0; c < 4; c++)
#pragma unroll
            for (int r = 0; r < 4; r++) {
                const float p = __expf(acc[c][r] - m_fin[r]) * inv_l[r];
                lds_p[wave][quad * 4 + r][c * 16 + lrow] = (__bf16)p;
                attn_base[(size_t)(qw + quad * 4 + r) * NV + kv0 + c * 16 + lrow] = p;
            }

        // PV: A = P (LDS, A-layout), B = K (kT, contiguous in kv).
        // Same-wave LDS RAW: compiler-inserted lgkmcnt; stripes wave-private.
#pragma unroll
        for (int kss = 0; kss < 2; kss++) {
            bf16x8 ap = load8(&lds_p[wave][lrow][kss * 32 + lk8]);
#pragma unroll
            for (int ct = 0; ct < 8; ct++) {
                bf16x8 bk = load8(kT_base + (size_t)(ct * 16 + lrow) * NV + kv0 + kss * 32 + lk8);
                oacc[ct] = __builtin_amdgcn_mfma_f32_16x16x32_bf16(ap, bk, oacc[ct], 0, 0, 0);
            }
        }
    }

    // ---- sum the two halves' partial O through LDS, half 0 writes out ----
    if (half == 1) {
#pragma unroll
        for (int ct = 0; ct < 8; ct++)
#pragma unroll
            for (int r = 0; r < 4; r++)
                obuf[wq * 16 + quad * 4 + r][ct * 16 + lrow] = oacc[ct][r];
    }
    __syncthreads();
    if (half == 0) {
#pragma unroll
        for (int ct = 0; ct < 8; ct++)
#pragma unroll
            for (int r = 0; r < 4; r++) {
                const int qrow = qw + quad * 4 + r;
                const int dcol = ct * 16 + lrow;
                out[(size_t)(b * NT + qrow) * TDIM + h * DHEAD + dcol] =
                    oacc[ct][r] + obuf[wq * 16 + quad * 4 + r][dcol];
            }
    }
}

// ---------------------------------------------------------------------------
extern "C" void kernel_launch(void* const* d_in, const int* in_sizes, int n_in,
                              void* d_out, int out_size, void* d_ws, size_t ws_size,
                              hipStream_t stream)
{
    const float* visual  = (const float*)d_in[0];   // [B, NV, VDIM] fp32
    const float* textual = (const float*)d_in[1];   // [B, NT, TDIM] fp32
    const float* W       = (const float*)d_in[2];   // [TDIM, VDIM] fp32

    float* out  = (float*)d_out;                     // [B, NT, TDIM]
    float* attn = out + (size_t)BB * NT * TDIM;      // [B*H, NT, NV]

    const size_t VC_ELEMS = (size_t)BB * NV * TDIM;  // 16,777,216
    __bf16* vc_hi = (__bf16*)d_ws;
    __bf16* vc_lo = vc_hi + VC_ELEMS;
    __bf16* kT    = vc_lo + VC_ELEMS;                // ws total ~100.7 MB (as round-0)

    gemm1_kernel<<<dim3(TDIM / 128, (BB * NV) / 128), 256, 0, stream>>>(
        visual, W, vc_hi, vc_lo);
    transpose_kernel<<<dim3(NV / 64, DHEAD / 64, BB * HEADS), 256, 0, stream>>>(
        vc_hi, kT);
    attn_kernel<<<dim3(NT / 64, BB * HEADS), 512, 0, stream>>>(
        textual, vc_hi, vc_lo, kT, out, attn);
}

// Round 4
// 1271.976 us; speedup vs baseline: 1.5804x; 1.5164x over previous
//
#include <hip/hip_runtime.h>
#include <hip/hip_bf16.h>
#include <math.h>

// Problem constants. Inputs/outputs are fp32 (reference dtype); MFMA compute
// uses bf16 hi+lo compensated splitting for fp32-accurate logits.
#define BB    4
#define NV    4096
#define NT    1024
#define VDIM  1024
#define TDIM  1024
#define HEADS 8
#define DHEAD 128   // TDIM / HEADS
#define KVBLK 64
#define NTILES (NV / KVBLK)   // 64

typedef __bf16 bf16x8 __attribute__((ext_vector_type(8)));
typedef float  f32x4  __attribute__((ext_vector_type(4)));

__device__ __forceinline__ bf16x8 load8(const __bf16* p) {
    return *reinterpret_cast<const bf16x8*>(p);
}
__device__ __forceinline__ void store8(__bf16* p, bf16x8 v) {
    *reinterpret_cast<bf16x8*>(p) = v;
}
// Async global->LDS 16B copy (lands at wave-uniform LDS base + lane*16).
__device__ __forceinline__ void async16(const __bf16* g, __bf16* l) {
    __builtin_amdgcn_global_load_lds(
        (const __attribute__((address_space(1))) unsigned int*)g,
        (__attribute__((address_space(3))) unsigned int*)l, 16, 0, 0);
}
// Load 8 fp32, split each into bf16 hi + bf16 lo (x = hi + lo + O(2^-18 x)).
__device__ __forceinline__ void split8(const float* __restrict__ p,
                                       bf16x8& hi, bf16x8& lo) {
    const f32x4 v0 = *reinterpret_cast<const f32x4*>(p);
    const f32x4 v1 = *reinterpret_cast<const f32x4*>(p + 4);
#pragma unroll
    for (int j = 0; j < 4; j++) {
        const __bf16 h0 = (__bf16)v0[j];
        hi[j] = h0; lo[j] = (__bf16)(v0[j] - (float)h0);
        const __bf16 h1 = (__bf16)v1[j];
        hi[4 + j] = h1; lo[4 + j] = (__bf16)(v1[j] - (float)h1);
    }
}

// ---------------------------------------------------------------------------
// Kernel 1: vc = visual @ W^T  (fp32 in, fp32-accurate via 3-MFMA hi/lo).
// (unchanged from the harness-verified round-0 kernel)
// ---------------------------------------------------------------------------
__global__ __launch_bounds__(256) void gemm1_kernel(
    const float* __restrict__ visual,   // [B*NV, VDIM]
    const float* __restrict__ W,        // [TDIM, VDIM]
    __bf16* __restrict__ vc_hi,         // [B*NV, TDIM]
    __bf16* __restrict__ vc_lo)
{
    const int lane = threadIdx.x & 63;
    const int wave = threadIdx.x >> 6;
    const int wm = wave >> 1, wn = wave & 1;
    const int m0 = blockIdx.y * 128 + wm * 64;
    const int n0 = blockIdx.x * 128 + wn * 64;
    const int lrow = lane & 15;
    const int lk8  = (lane >> 4) * 8;

    f32x4 acc[4][4];
#pragma unroll
    for (int i = 0; i < 4; i++)
#pragma unroll
        for (int j = 0; j < 4; j++) acc[i][j] = (f32x4){0.f, 0.f, 0.f, 0.f};

    for (int k0 = 0; k0 < VDIM; k0 += 32) {
        bf16x8 bh[4], bl[4];
#pragma unroll
        for (int nt = 0; nt < 4; nt++)
            split8(W + (size_t)(n0 + nt * 16 + lrow) * VDIM + k0 + lk8, bh[nt], bl[nt]);
#pragma unroll
        for (int mt = 0; mt < 4; mt++) {
            bf16x8 ah, al;
            split8(visual + (size_t)(m0 + mt * 16 + lrow) * VDIM + k0 + lk8, ah, al);
#pragma unroll
            for (int nt = 0; nt < 4; nt++) {
                acc[mt][nt] = __builtin_amdgcn_mfma_f32_16x16x32_bf16(ah, bh[nt], acc[mt][nt], 0, 0, 0);
                acc[mt][nt] = __builtin_amdgcn_mfma_f32_16x16x32_bf16(ah, bl[nt], acc[mt][nt], 0, 0, 0);
                acc[mt][nt] = __builtin_amdgcn_mfma_f32_16x16x32_bf16(al, bh[nt], acc[mt][nt], 0, 0, 0);
            }
        }
    }

    const int r0 = (lane >> 4) * 4;
#pragma unroll
    for (int mt = 0; mt < 4; mt++)
#pragma unroll
        for (int nt = 0; nt < 4; nt++)
#pragma unroll
            for (int r = 0; r < 4; r++) {
                const int row = m0 + mt * 16 + r0 + r;
                const int col = n0 + nt * 16 + lrow;
                const float v = acc[mt][nt][r];
                const __bf16 h = (__bf16)v;          // RNE
                const __bf16 lo = (__bf16)(v - (float)h);
                const size_t idx = (size_t)row * TDIM + col;
                vc_hi[idx] = h;
                vc_lo[idx] = lo;
            }
}

// ---------------------------------------------------------------------------
// Kernel 2: kT[bh][d][kv] = vc_hi[b][kv][h*128+d]  (unchanged)
// ---------------------------------------------------------------------------
__global__ __launch_bounds__(256) void transpose_kernel(
    const __bf16* __restrict__ vc_hi,   // [B, NV, TDIM]
    __bf16* __restrict__ kT)            // [B*H, DHEAD, NV]
{
    __shared__ __bf16 tile[64][72];
    const int bh = blockIdx.z;
    const int b = bh >> 3, h = bh & 7;
    const int kv0 = blockIdx.x * 64;
    const int d0  = blockIdx.y * 64;
    const int t = threadIdx.x;

#pragma unroll
    for (int it = 0; it < 2; it++) {
        const int kvl = (t >> 3) + it * 32;
        const int dl  = (t & 7) * 8;
        bf16x8 v = load8(vc_hi + (size_t)(b * NV + kv0 + kvl) * TDIM + h * DHEAD + d0 + dl);
#pragma unroll
        for (int j = 0; j < 8; j++) tile[kvl][dl + j] = v[j];
    }
    __syncthreads();
#pragma unroll
    for (int it = 0; it < 2; it++) {
        const int dl  = (t >> 3) + it * 32;
        const int kvl = (t & 7) * 8;
        bf16x8 v;
#pragma unroll
        for (int j = 0; j < 8; j++) v[j] = tile[kvl + j][dl];
        store8(kT + (size_t)(bh * DHEAD + d0 + dl) * NV + kv0 + kvl, v);
    }
}

// ---------------------------------------------------------------------------
// Kernel 3: fused attention, 4 waves (256 thr), 64 q-rows/block.
// CHANGE vs round 3: K hi/lo tiles are LDS-staged ONCE per block via
// global_load_lds (dbuf, 1 barrier/tile) and shared by all 4 waves — round-3
// showed occupancy 24->48% bought only -7% (not occupancy-bound); the real
// cost is 4 waves x 2 passes redundantly streaming the same K rows: ~41 MB/CU
// of L2 traffic with a 48 KB/tile working set that thrashes the 32 KB L1.
// Staging cuts global-load instructions ~8x; kT stays global (16 KB/tile now
// L1-fits once K is out of L1).
// Bank conflicts: [64][128]bf16 rows are 256B (all rows bank 0) -> 16B-chunk
// XOR swizzle chunk^=(kv&7) (G4-proven), applied on the *global source* at
// staging (global_load_lds dest must stay linear, m173) and on the LDS read.
// LDS: kbuf 64 KB + P stripes 9 KB = 73 KB -> 2 blocks/CU. Occupancy will
// READ ~24% — intentional, proven non-binding.
// Numerics identical to the harness-verified round-0 kernel (single kv
// stream, same MFMA order, same softmax).
// ---------------------------------------------------------------------------
__global__ __launch_bounds__(256, 2) void attn_kernel(
    const float* __restrict__ textual,  // [B, NT, TDIM] fp32
    const __bf16* __restrict__ vc_hi,   // [B, NV, TDIM]
    const __bf16* __restrict__ vc_lo,
    const __bf16* __restrict__ kT,      // [B*H, DHEAD, NV]
    float* __restrict__ out,            // [B, NT, TDIM] fp32
    float* __restrict__ attn)           // [B*H, NT, NV] fp32
{
    __shared__ __bf16 kbuf[2][2][KVBLK][128]; // [dbuf][hi/lo][kv][d], 64 KB
    __shared__ __bf16 lds_p[4][16][72];       // wave-private P stripes, 9 KB

    const int bh = blockIdx.y;
    const int b = bh >> 3, h = bh & 7;
    const int q0 = blockIdx.x * 64;
    const int lane = threadIdx.x & 63;
    const int wave = threadIdx.x >> 6;  // 0..3
    const int lrow = lane & 15;
    const int quad = lane >> 4;
    const int lk8  = quad * 8;
    const int qw = q0 + wave * 16;      // this wave's q base
    const int sw = lrow & 7;            // read-side swizzle key

    // Q fragments (hi/lo): A[m=lane&15][k], d=128 -> 4 k-steps of 32
    bf16x8 qh[4], ql[4];
#pragma unroll
    for (int ks = 0; ks < 4; ks++)
        split8(textual + (size_t)(b * NT + qw + lrow) * TDIM + h * DHEAD + ks * 32 + lk8,
               qh[ks], ql[ks]);

    const __bf16* khi_base = vc_hi + (size_t)b * NV * TDIM + h * DHEAD;
    const __bf16* klo_base = vc_lo + (size_t)b * NV * TDIM + h * DHEAD;

    // Stage tile kt into kbuf[d]: 1024 16B-chunks per array, 4 issues/thread.
    // LDS dest linear in cidx; global source chunk pre-swizzled ch^(kv&7)
    // so that LDS[kv][chunk'] holds global chunk'^(kv&7) (involution).
    const int tid = (int)threadIdx.x;
    auto stage = [&](int kt, int d) {
        const int kv0s = kt * KVBLK;
#pragma unroll
        for (int i = 0; i < 4; i++) {
            const int cidx = i * 256 + tid;
            const int kv = cidx >> 4;                 // 0..63
            const int ch = (cidx & 15) ^ (kv & 7);    // source chunk
            const size_t goff = (size_t)(kv0s + kv) * TDIM + ch * 8;
            const int lbase = (i * 256 + (tid & ~63)) * 8;  // wave-uniform
            async16(khi_base + goff, &kbuf[d][0][0][0] + lbase);
            async16(klo_base + goff, &kbuf[d][1][0][0] + lbase);
        }
    };

    float m_run[4], l_run[4];
#pragma unroll
    for (int r = 0; r < 4; r++) { m_run[r] = -INFINITY; l_run[r] = 0.f; }

    // ---- pass 1: running max & denom ----
    stage(0, 0);
    __syncthreads();
    for (int kt = 0; kt < NTILES; kt++) {
        const int cur = kt & 1;
        if (kt + 1 < NTILES) stage(kt + 1, cur ^ 1);
        f32x4 acc[4];
#pragma unroll
        for (int c = 0; c < 4; c++) acc[c] = (f32x4){0.f, 0.f, 0.f, 0.f};
#pragma unroll
        for (int c = 0; c < 4; c++) {
#pragma unroll
            for (int ks = 0; ks < 4; ks++) {
                const int sc = ((ks * 4 + quad) ^ sw) * 8;
                bf16x8 kh = load8(&kbuf[cur][0][c * 16 + lrow][sc]);
                bf16x8 kl = load8(&kbuf[cur][1][c * 16 + lrow][sc]);
                acc[c] = __builtin_amdgcn_mfma_f32_16x16x32_bf16(qh[ks], kh, acc[c], 0, 0, 0);
                acc[c] = __builtin_amdgcn_mfma_f32_16x16x32_bf16(qh[ks], kl, acc[c], 0, 0, 0);
                acc[c] = __builtin_amdgcn_mfma_f32_16x16x32_bf16(ql[ks], kh, acc[c], 0, 0, 0);
            }
        }
#pragma unroll
        for (int r = 0; r < 4; r++) {
            float tm = fmaxf(fmaxf(acc[0][r], acc[1][r]), fmaxf(acc[2][r], acc[3][r]));
#pragma unroll
            for (int off = 1; off < 16; off <<= 1)
                tm = fmaxf(tm, __shfl_xor(tm, off, 64));
            const float nm = fmaxf(m_run[r], tm);
            float ps = __expf(acc[0][r] - nm) + __expf(acc[1][r] - nm) +
                       __expf(acc[2][r] - nm) + __expf(acc[3][r] - nm);
#pragma unroll
            for (int off = 1; off < 16; off <<= 1)
                ps += __shfl_xor(ps, off, 64);
            l_run[r] = l_run[r] * __expf(m_run[r] - nm) + ps;
            m_run[r] = nm;
        }
        __syncthreads();   // drains stage(kt+1) + guards kbuf[cur] reuse
    }

    float inv_l[4];
#pragma unroll
    for (int r = 0; r < 4; r++) inv_l[r] = 1.0f / l_run[r];

    f32x4 oacc[8];
#pragma unroll
    for (int c = 0; c < 8; c++) oacc[c] = (f32x4){0.f, 0.f, 0.f, 0.f};

    float* attn_base = attn + (size_t)bh * NT * NV;
    const __bf16* kT_base = kT + (size_t)bh * DHEAD * NV;

    // ---- pass 2: recompute S, emit normalized attn, accumulate O ----
    stage(0, 0);
    __syncthreads();
    for (int kt = 0; kt < NTILES; kt++) {
        const int cur = kt & 1;
        const int kv0 = kt * KVBLK;
        if (kt + 1 < NTILES) stage(kt + 1, cur ^ 1);
        f32x4 acc[4];
#pragma unroll
        for (int c = 0; c < 4; c++) acc[c] = (f32x4){0.f, 0.f, 0.f, 0.f};
#pragma unroll
        for (int c = 0; c < 4; c++) {
#pragma unroll
            for (int ks = 0; ks < 4; ks++) {
                const int sc = ((ks * 4 + quad) ^ sw) * 8;
                bf16x8 kh = load8(&kbuf[cur][0][c * 16 + lrow][sc]);
                bf16x8 kl = load8(&kbuf[cur][1][c * 16 + lrow][sc]);
                acc[c] = __builtin_amdgcn_mfma_f32_16x16x32_bf16(qh[ks], kh, acc[c], 0, 0, 0);
                acc[c] = __builtin_amdgcn_mfma_f32_16x16x32_bf16(qh[ks], kl, acc[c], 0, 0, 0);
                acc[c] = __builtin_amdgcn_mfma_f32_16x16x32_bf16(ql[ks], kh, acc[c], 0, 0, 0);
            }
        }
        // p: fp32 -> attn directly (coalesced 64B per 16-lane group);
        // bf16 -> wave-private LDS stripe for the PV A-operand transpose.
#pragma unroll
        for (int c = 0; c < 4; c++)
#pragma unroll
            for (int r = 0; r < 4; r++) {
                const float p = __expf(acc[c][r] - m_run[r]) * inv_l[r];
                lds_p[wave][quad * 4 + r][c * 16 + lrow] = (__bf16)p;
                attn_base[(size_t)(qw + quad * 4 + r) * NV + kv0 + c * 16 + lrow] = p;
            }

        // PV: A = P (LDS, A-layout), B = K (kT global; 16 KB tile L1-hits
        // across the 4 waves now that K streams through LDS instead of L1).
#pragma unroll
        for (int kss = 0; kss < 2; kss++) {
            bf16x8 ap = load8(&lds_p[wave][lrow][kss * 32 + lk8]);
#pragma unroll
            for (int ct = 0; ct < 8; ct++) {
                bf16x8 bk = load8(kT_base + (size_t)(ct * 16 + lrow) * NV + kv0 + kss * 32 + lk8);
                oacc[ct] = __builtin_amdgcn_mfma_f32_16x16x32_bf16(ap, bk, oacc[ct], 0, 0, 0);
            }
        }
        __syncthreads();
    }

    // epilogue: out[b, q, h*128+d] fp32 (round-0 style, per wave)
#pragma unroll
    for (int ct = 0; ct < 8; ct++)
#pragma unroll
        for (int r = 0; r < 4; r++) {
            const int qrow = qw + quad * 4 + r;
            const int dcol = ct * 16 + lrow;
            out[(size_t)(b * NT + qrow) * TDIM + h * DHEAD + dcol] = oacc[ct][r];
        }
}

// ---------------------------------------------------------------------------
extern "C" void kernel_launch(void* const* d_in, const int* in_sizes, int n_in,
                              void* d_out, int out_size, void* d_ws, size_t ws_size,
                              hipStream_t stream)
{
    const float* visual  = (const float*)d_in[0];   // [B, NV, VDIM] fp32
    const float* textual = (const float*)d_in[1];   // [B, NT, TDIM] fp32
    const float* W       = (const float*)d_in[2];   // [TDIM, VDIM] fp32

    float* out  = (float*)d_out;                     // [B, NT, TDIM]
    float* attn = out + (size_t)BB * NT * TDIM;      // [B*H, NT, NV]

    const size_t VC_ELEMS = (size_t)BB * NV * TDIM;  // 16,777,216
    __bf16* vc_hi = (__bf16*)d_ws;
    __bf16* vc_lo = vc_hi + VC_ELEMS;
    __bf16* kT    = vc_lo + VC_ELEMS;                // ws total ~100.7 MB (proven)

    gemm1_kernel<<<dim3(TDIM / 128, (BB * NV) / 128), 256, 0, stream>>>(
        visual, W, vc_hi, vc_lo);
    transpose_kernel<<<dim3(NV / 64, DHEAD / 64, BB * HEADS), 256, 0, stream>>>(
        vc_hi, kT);
    attn_kernel<<<dim3(NT / 64, BB * HEADS), 256, 0, stream>>>(
        textual, vc_hi, vc_lo, kT, out, attn);
}

// Round 5
// 1163.851 us; speedup vs baseline: 1.7272x; 1.0929x over previous
//
#include <hip/hip_runtime.h>
#include <hip/hip_bf16.h>
#include <math.h>

// Problem constants. Inputs/outputs are fp32 (reference dtype); MFMA compute
// uses bf16 hi+lo compensated splitting for fp32-accurate logits.
#define BB    4
#define NV    4096
#define NT    1024
#define VDIM  1024
#define TDIM  1024
#define HEADS 8
#define DHEAD 128   // TDIM / HEADS
#define KVBLK 64
#define NTILES (NV / KVBLK)   // 64

typedef __bf16 bf16x8 __attribute__((ext_vector_type(8)));
typedef float  f32x4  __attribute__((ext_vector_type(4)));

__device__ __forceinline__ bf16x8 load8(const __bf16* p) {
    return *reinterpret_cast<const bf16x8*>(p);
}
__device__ __forceinline__ void store8(__bf16* p, bf16x8 v) {
    *reinterpret_cast<bf16x8*>(p) = v;
}
// Async global->LDS 16B copy (lands at wave-uniform LDS base + lane*16).
__device__ __forceinline__ void async16(const void* g, void* l) {
    __builtin_amdgcn_global_load_lds(
        (const __attribute__((address_space(1))) unsigned int*)g,
        (__attribute__((address_space(3))) unsigned int*)l, 16, 0, 0);
}
// Load 8 fp32, split each into bf16 hi + bf16 lo (x = hi + lo + O(2^-18 x)).
__device__ __forceinline__ void split8(const float* __restrict__ p,
                                       bf16x8& hi, bf16x8& lo) {
    const f32x4 v0 = *reinterpret_cast<const f32x4*>(p);
    const f32x4 v1 = *reinterpret_cast<const f32x4*>(p + 4);
#pragma unroll
    for (int j = 0; j < 4; j++) {
        const __bf16 h0 = (__bf16)v0[j];
        hi[j] = h0; lo[j] = (__bf16)(v0[j] - (float)h0);
        const __bf16 h1 = (__bf16)v1[j];
        hi[4 + j] = h1; lo[4 + j] = (__bf16)(v1[j] - (float)h1);
    }
}
// Same split from two register f32x4 (LDS-sourced).
__device__ __forceinline__ void split44(const f32x4 v0, const f32x4 v1,
                                        bf16x8& hi, bf16x8& lo) {
#pragma unroll
    for (int j = 0; j < 4; j++) {
        const __bf16 h0 = (__bf16)v0[j];
        hi[j] = h0; lo[j] = (__bf16)(v0[j] - (float)h0);
        const __bf16 h1 = (__bf16)v1[j];
        hi[4 + j] = h1; lo[4 + j] = (__bf16)(v1[j] - (float)h1);
    }
}

// ---------------------------------------------------------------------------
// Kernel 1: vc = visual @ W^T  (fp32 in, fp32-accurate via 3-MFMA hi/lo).
// CHANGE vs round 4: LDS-staged + double-buffered via global_load_lds —
// the old version issued 16 dependent 32B global loads per k-step feeding
// MFMA immediately (no prefetch distance) and sat ~16x above its MFMA/VALU
// floors (~680 us, latency-bound), the same disease staging just cured in
// attn. Stage tile k+1 while computing tile k; fp32 tiles in LDS, split8
// from LDS registers. Chunk-XOR swizzle (sc = lc ^ (row&7)) applied on the
// GLOBAL SOURCE at staging (LDS dest must stay linear, m173) and inverted
// on the LDS read.
// 128x128 block tile, BK=32, 4 waves of 64x64. LDS 64 KB -> 2 blocks/CU.
// ---------------------------------------------------------------------------
__global__ __launch_bounds__(256, 2) void gemm1_kernel(
    const float* __restrict__ visual,   // [B*NV, VDIM]
    const float* __restrict__ W,        // [TDIM, VDIM]
    __bf16* __restrict__ vc_hi,         // [B*NV, TDIM]
    __bf16* __restrict__ vc_lo)
{
    __shared__ float Abuf[2][128][32];  // 32 KB (visual tile, [row][k])
    __shared__ float Bbuf[2][128][32];  // 32 KB (W tile, [row][k])

    const int lane = threadIdx.x & 63;
    const int wave = threadIdx.x >> 6;
    const int wm = wave >> 1, wn = wave & 1;
    const int bm0 = blockIdx.y * 128;
    const int bn0 = blockIdx.x * 128;
    const int lrow = lane & 15;
    const int quad = lane >> 4;
    const int tid = (int)threadIdx.x;

    f32x4 acc[4][4];
#pragma unroll
    for (int i = 0; i < 4; i++)
#pragma unroll
        for (int j = 0; j < 4; j++) acc[i][j] = (f32x4){0.f, 0.f, 0.f, 0.f};

    // Stage one 128x32 fp32 tile pair at k0 into buffer d.
    // 1024 16B-chunks per array, 4 issues/thread each. LDS dest linear in
    // cidx; global source chunk pre-swizzled sc = lc ^ (row&7) (involution)
    // so LDS[row][lc] holds global chunk (row, lc^(row&7)).
    auto stage = [&](int k0, int d) {
#pragma unroll
        for (int i = 0; i < 4; i++) {
            const int cidx = i * 256 + tid;
            const int row = cidx >> 3;                // 0..127
            const int sc  = (cidx & 7) ^ (row & 7);   // source chunk 0..7
            const int lbase = (i * 256 + (tid & ~63)) * 4;  // wave-uniform, floats
            async16(visual + (size_t)(bm0 + row) * VDIM + k0 + sc * 4,
                    &Abuf[d][0][0] + lbase);
            async16(W + (size_t)(bn0 + row) * VDIM + k0 + sc * 4,
                    &Bbuf[d][0][0] + lbase);
        }
    };

    stage(0, 0);
    __syncthreads();   // compiler drains vmcnt before s_barrier

    for (int ks = 0; ks < VDIM / 32; ks++) {
        const int cur = ks & 1;
        if (ks + 1 < VDIM / 32) stage((ks + 1) * 32, cur ^ 1);

        // B fragments: global chunk gc = quad*2 + {0,1} at LDS lc = gc^(row&7)
        bf16x8 bh[4], bl[4];
#pragma unroll
        for (int nt = 0; nt < 4; nt++) {
            const int row = wn * 64 + nt * 16 + lrow;
            const int c0 = (quad * 2) ^ (row & 7);
            const int c1 = (quad * 2 + 1) ^ (row & 7);
            const f32x4 v0 = *reinterpret_cast<const f32x4*>(&Bbuf[cur][row][c0 * 4]);
            const f32x4 v1 = *reinterpret_cast<const f32x4*>(&Bbuf[cur][row][c1 * 4]);
            split44(v0, v1, bh[nt], bl[nt]);
        }
#pragma unroll
        for (int mt = 0; mt < 4; mt++) {
            const int row = wm * 64 + mt * 16 + lrow;
            const int c0 = (quad * 2) ^ (row & 7);
            const int c1 = (quad * 2 + 1) ^ (row & 7);
            const f32x4 v0 = *reinterpret_cast<const f32x4*>(&Abuf[cur][row][c0 * 4]);
            const f32x4 v1 = *reinterpret_cast<const f32x4*>(&Abuf[cur][row][c1 * 4]);
            bf16x8 ah, al;
            split44(v0, v1, ah, al);
#pragma unroll
            for (int nt = 0; nt < 4; nt++) {
                acc[mt][nt] = __builtin_amdgcn_mfma_f32_16x16x32_bf16(ah, bh[nt], acc[mt][nt], 0, 0, 0);
                acc[mt][nt] = __builtin_amdgcn_mfma_f32_16x16x32_bf16(ah, bl[nt], acc[mt][nt], 0, 0, 0);
                acc[mt][nt] = __builtin_amdgcn_mfma_f32_16x16x32_bf16(al, bh[nt], acc[mt][nt], 0, 0, 0);
            }
        }
        __syncthreads();   // drains stage(ks+1) + guards buffer reuse
    }

    const int m0 = bm0 + wm * 64;
    const int n0 = bn0 + wn * 64;
    const int r0 = quad * 4;
#pragma unroll
    for (int mt = 0; mt < 4; mt++)
#pragma unroll
        for (int nt = 0; nt < 4; nt++)
#pragma unroll
            for (int r = 0; r < 4; r++) {
                const int row = m0 + mt * 16 + r0 + r;
                const int col = n0 + nt * 16 + lrow;
                const float v = acc[mt][nt][r];
                const __bf16 h = (__bf16)v;          // RNE
                const __bf16 lo = (__bf16)(v - (float)h);
                const size_t idx = (size_t)row * TDIM + col;
                vc_hi[idx] = h;
                vc_lo[idx] = lo;
            }
}

// ---------------------------------------------------------------------------
// Kernel 2: kT[bh][d][kv] = vc_hi[b][kv][h*128+d]  (unchanged)
// ---------------------------------------------------------------------------
__global__ __launch_bounds__(256) void transpose_kernel(
    const __bf16* __restrict__ vc_hi,   // [B, NV, TDIM]
    __bf16* __restrict__ kT)            // [B*H, DHEAD, NV]
{
    __shared__ __bf16 tile[64][72];
    const int bh = blockIdx.z;
    const int b = bh >> 3, h = bh & 7;
    const int kv0 = blockIdx.x * 64;
    const int d0  = blockIdx.y * 64;
    const int t = threadIdx.x;

#pragma unroll
    for (int it = 0; it < 2; it++) {
        const int kvl = (t >> 3) + it * 32;
        const int dl  = (t & 7) * 8;
        bf16x8 v = load8(vc_hi + (size_t)(b * NV + kv0 + kvl) * TDIM + h * DHEAD + d0 + dl);
#pragma unroll
        for (int j = 0; j < 8; j++) tile[kvl][dl + j] = v[j];
    }
    __syncthreads();
#pragma unroll
    for (int it = 0; it < 2; it++) {
        const int dl  = (t >> 3) + it * 32;
        const int kvl = (t & 7) * 8;
        bf16x8 v;
#pragma unroll
        for (int j = 0; j < 8; j++) v[j] = tile[kvl + j][dl];
        store8(kT + (size_t)(bh * DHEAD + d0 + dl) * NV + kv0 + kvl, v);
    }
}

// ---------------------------------------------------------------------------
// Kernel 3: fused attention, 4 waves (256 thr), 64 q-rows/block.
// (unchanged from round 4: LDS-staged K hi/lo, dbuf, source-swizzled;
// 1237 -> 570 us verified)
// ---------------------------------------------------------------------------
__global__ __launch_bounds__(256, 2) void attn_kernel(
    const float* __restrict__ textual,  // [B, NT, TDIM] fp32
    const __bf16* __restrict__ vc_hi,   // [B, NV, TDIM]
    const __bf16* __restrict__ vc_lo,
    const __bf16* __restrict__ kT,      // [B*H, DHEAD, NV]
    float* __restrict__ out,            // [B, NT, TDIM] fp32
    float* __restrict__ attn)           // [B*H, NT, NV] fp32
{
    __shared__ __bf16 kbuf[2][2][KVBLK][128]; // [dbuf][hi/lo][kv][d], 64 KB
    __shared__ __bf16 lds_p[4][16][72];       // wave-private P stripes, 9 KB

    const int bh = blockIdx.y;
    const int b = bh >> 3, h = bh & 7;
    const int q0 = blockIdx.x * 64;
    const int lane = threadIdx.x & 63;
    const int wave = threadIdx.x >> 6;  // 0..3
    const int lrow = lane & 15;
    const int quad = lane >> 4;
    const int lk8  = quad * 8;
    const int qw = q0 + wave * 16;      // this wave's q base
    const int sw = lrow & 7;            // read-side swizzle key

    // Q fragments (hi/lo): A[m=lane&15][k], d=128 -> 4 k-steps of 32
    bf16x8 qh[4], ql[4];
#pragma unroll
    for (int ks = 0; ks < 4; ks++)
        split8(textual + (size_t)(b * NT + qw + lrow) * TDIM + h * DHEAD + ks * 32 + lk8,
               qh[ks], ql[ks]);

    const __bf16* khi_base = vc_hi + (size_t)b * NV * TDIM + h * DHEAD;
    const __bf16* klo_base = vc_lo + (size_t)b * NV * TDIM + h * DHEAD;

    // Stage tile kt into kbuf[d]: 1024 16B-chunks per array, 4 issues/thread.
    const int tid = (int)threadIdx.x;
    auto stage = [&](int kt, int d) {
        const int kv0s = kt * KVBLK;
#pragma unroll
        for (int i = 0; i < 4; i++) {
            const int cidx = i * 256 + tid;
            const int kv = cidx >> 4;                 // 0..63
            const int ch = (cidx & 15) ^ (kv & 7);    // source chunk
            const size_t goff = (size_t)(kv0s + kv) * TDIM + ch * 8;
            const int lbase = (i * 256 + (tid & ~63)) * 8;  // wave-uniform
            async16(khi_base + goff, &kbuf[d][0][0][0] + lbase);
            async16(klo_base + goff, &kbuf[d][1][0][0] + lbase);
        }
    };

    float m_run[4], l_run[4];
#pragma unroll
    for (int r = 0; r < 4; r++) { m_run[r] = -INFINITY; l_run[r] = 0.f; }

    // ---- pass 1: running max & denom ----
    stage(0, 0);
    __syncthreads();
    for (int kt = 0; kt < NTILES; kt++) {
        const int cur = kt & 1;
        if (kt + 1 < NTILES) stage(kt + 1, cur ^ 1);
        f32x4 acc[4];
#pragma unroll
        for (int c = 0; c < 4; c++) acc[c] = (f32x4){0.f, 0.f, 0.f, 0.f};
#pragma unroll
        for (int c = 0; c < 4; c++) {
#pragma unroll
            for (int ks = 0; ks < 4; ks++) {
                const int sc = ((ks * 4 + quad) ^ sw) * 8;
                bf16x8 kh = load8(&kbuf[cur][0][c * 16 + lrow][sc]);
                bf16x8 kl = load8(&kbuf[cur][1][c * 16 + lrow][sc]);
                acc[c] = __builtin_amdgcn_mfma_f32_16x16x32_bf16(qh[ks], kh, acc[c], 0, 0, 0);
                acc[c] = __builtin_amdgcn_mfma_f32_16x16x32_bf16(qh[ks], kl, acc[c], 0, 0, 0);
                acc[c] = __builtin_amdgcn_mfma_f32_16x16x32_bf16(ql[ks], kh, acc[c], 0, 0, 0);
            }
        }
#pragma unroll
        for (int r = 0; r < 4; r++) {
            float tm = fmaxf(fmaxf(acc[0][r], acc[1][r]), fmaxf(acc[2][r], acc[3][r]));
#pragma unroll
            for (int off = 1; off < 16; off <<= 1)
                tm = fmaxf(tm, __shfl_xor(tm, off, 64));
            const float nm = fmaxf(m_run[r], tm);
            float ps = __expf(acc[0][r] - nm) + __expf(acc[1][r] - nm) +
                       __expf(acc[2][r] - nm) + __expf(acc[3][r] - nm);
#pragma unroll
            for (int off = 1; off < 16; off <<= 1)
                ps += __shfl_xor(ps, off, 64);
            l_run[r] = l_run[r] * __expf(m_run[r] - nm) + ps;
            m_run[r] = nm;
        }
        __syncthreads();   // drains stage(kt+1) + guards kbuf[cur] reuse
    }

    float inv_l[4];
#pragma unroll
    for (int r = 0; r < 4; r++) inv_l[r] = 1.0f / l_run[r];

    f32x4 oacc[8];
#pragma unroll
    for (int c = 0; c < 8; c++) oacc[c] = (f32x4){0.f, 0.f, 0.f, 0.f};

    float* attn_base = attn + (size_t)bh * NT * NV;
    const __bf16* kT_base = kT + (size_t)bh * DHEAD * NV;

    // ---- pass 2: recompute S, emit normalized attn, accumulate O ----
    stage(0, 0);
    __syncthreads();
    for (int kt = 0; kt < NTILES; kt++) {
        const int cur = kt & 1;
        const int kv0 = kt * KVBLK;
        if (kt + 1 < NTILES) stage(kt + 1, cur ^ 1);
        f32x4 acc[4];
#pragma unroll
        for (int c = 0; c < 4; c++) acc[c] = (f32x4){0.f, 0.f, 0.f, 0.f};
#pragma unroll
        for (int c = 0; c < 4; c++) {
#pragma unroll
            for (int ks = 0; ks < 4; ks++) {
                const int sc = ((ks * 4 + quad) ^ sw) * 8;
                bf16x8 kh = load8(&kbuf[cur][0][c * 16 + lrow][sc]);
                bf16x8 kl = load8(&kbuf[cur][1][c * 16 + lrow][sc]);
                acc[c] = __builtin_amdgcn_mfma_f32_16x16x32_bf16(qh[ks], kh, acc[c], 0, 0, 0);
                acc[c] = __builtin_amdgcn_mfma_f32_16x16x32_bf16(qh[ks], kl, acc[c], 0, 0, 0);
                acc[c] = __builtin_amdgcn_mfma_f32_16x16x32_bf16(ql[ks], kh, acc[c], 0, 0, 0);
            }
        }
        // p: fp32 -> attn directly (coalesced 64B per 16-lane group);
        // bf16 -> wave-private LDS stripe for the PV A-operand transpose.
#pragma unroll
        for (int c = 0; c < 4; c++)
#pragma unroll
            for (int r = 0; r < 4; r++) {
                const float p = __expf(acc[c][r] - m_run[r]) * inv_l[r];
                lds_p[wave][quad * 4 + r][c * 16 + lrow] = (__bf16)p;
                attn_base[(size_t)(qw + quad * 4 + r) * NV + kv0 + c * 16 + lrow] = p;
            }

        // PV: A = P (LDS, A-layout), B = K (kT global; 16 KB tile L1-hits
        // across the 4 waves now that K streams through LDS instead of L1).
#pragma unroll
        for (int kss = 0; kss < 2; kss++) {
            bf16x8 ap = load8(&lds_p[wave][lrow][kss * 32 + lk8]);
#pragma unroll
            for (int ct = 0; ct < 8; ct++) {
                bf16x8 bk = load8(kT_base + (size_t)(ct * 16 + lrow) * NV + kv0 + kss * 32 + lk8);
                oacc[ct] = __builtin_amdgcn_mfma_f32_16x16x32_bf16(ap, bk, oacc[ct], 0, 0, 0);
            }
        }
        __syncthreads();
    }

    // epilogue: out[b, q, h*128+d] fp32
#pragma unroll
    for (int ct = 0; ct < 8; ct++)
#pragma unroll
        for (int r = 0; r < 4; r++) {
            const int qrow = qw + quad * 4 + r;
            const int dcol = ct * 16 + lrow;
            out[(size_t)(b * NT + qrow) * TDIM + h * DHEAD + dcol] = oacc[ct][r];
        }
}

// ---------------------------------------------------------------------------
extern "C" void kernel_launch(void* const* d_in, const int* in_sizes, int n_in,
                              void* d_out, int out_size, void* d_ws, size_t ws_size,
                              hipStream_t stream)
{
    const float* visual  = (const float*)d_in[0];   // [B, NV, VDIM] fp32
    const float* textual = (const float*)d_in[1];   // [B, NT, TDIM] fp32
    const float* W       = (const float*)d_in[2];   // [TDIM, VDIM] fp32

    float* out  = (float*)d_out;                     // [B, NT, TDIM]
    float* attn = out + (size_t)BB * NT * TDIM;      // [B*H, NT, NV]

    const size_t VC_ELEMS = (size_t)BB * NV * TDIM;  // 16,777,216
    __bf16* vc_hi = (__bf16*)d_ws;
    __bf16* vc_lo = vc_hi + VC_ELEMS;
    __bf16* kT    = vc_lo + VC_ELEMS;                // ws total ~100.7 MB (proven)

    gemm1_kernel<<<dim3(TDIM / 128, (BB * NV) / 128), 256, 0, stream>>>(
        visual, W, vc_hi, vc_lo);
    transpose_kernel<<<dim3(NV / 64, DHEAD / 64, BB * HEADS), 256, 0, stream>>>(
        vc_hi, kT);
    attn_kernel<<<dim3(NT / 64, BB * HEADS), 256, 0, stream>>>(
        textual, vc_hi, vc_lo, kT, out, attn);
}